// Round 2
// baseline (532.277 us; speedup 1.0000x reference)
//
#include <hip/hip_runtime.h>

// Unpooling (2x2, stride 2, pad 0), B=32 C=64 H=W=112 -> Ho=Wo=224.
//
// DTYPES (round-1 post-mortem): feature_map fp32, switches int32, out fp32.
// Round-1's bf16 interpretation produced NaN -- impossible from finite bf16
// inputs through pure select/zero logic, but exactly what reading fp32 as
// bf16 halves yields (~1/256 of random low-halves are bf16-NaN patterns).
//
// Scatter inverted to gather/expand: input element (hi,wi) owns the disjoint
// 2x2 output block at (2hi, 2wi); switches in [0,4) picks the cell
// (s=0:(0,0) s=1:(0,1) s=2:(1,0) s=3:(1,1)), other 3 cells are zero.
// Every output element written exactly once -> no atomics, no zero-init.

#define BB 32
#define CC 64
#define HH 112
#define WW 112
#define HO 224
#define WO 224

__global__ __launch_bounds__(256) void unpool_kernel(
    const float* __restrict__ fm,
    const int*   __restrict__ sw,
    float*       __restrict__ out)
{
    const int tid = blockIdx.x * blockDim.x + threadIdx.x;
    // total threads = B*C*H*(W/2) = 12,845,056 ; grid sized exactly, no bounds check
    const int chunk = tid % (WW / 2);        // 2-wide chunk within the input row
    const int rowid = tid / (WW / 2);        // global input row index
    const int hi    = rowid % HH;
    const int plane = rowid / HH;            // b*C + c

    const int in_idx = tid * 2;              // flat input element index (contiguous)
    const float2 f = *(const float2*)(fm + in_idx);
    const int2   s = *(const int2*)(sw + in_idx);

    // s: 0 -> (dr=0,dc=0), 1 -> (0,1), 2 -> (1,0), 3 -> (1,1)
    float4 o_even, o_odd;
    o_even.x = (s.x == 0) ? f.x : 0.0f;
    o_even.y = (s.x == 1) ? f.x : 0.0f;
    o_even.z = (s.y == 0) ? f.y : 0.0f;
    o_even.w = (s.y == 1) ? f.y : 0.0f;
    o_odd.x  = (s.x == 2) ? f.x : 0.0f;
    o_odd.y  = (s.x == 3) ? f.x : 0.0f;
    o_odd.z  = (s.y == 2) ? f.y : 0.0f;
    o_odd.w  = (s.y == 3) ? f.y : 0.0f;

    const int out_base = plane * (HO * WO) + (hi * 2) * WO + chunk * 4;  // < 2^31
    *(float4*)(out + out_base)      = o_even;  // row 2*hi,   16B aligned
    *(float4*)(out + out_base + WO) = o_odd;   // row 2*hi+1, 16B aligned (224*4B pitch)
}

extern "C" void kernel_launch(void* const* d_in, const int* in_sizes, int n_in,
                              void* d_out, int out_size, void* d_ws, size_t ws_size,
                              hipStream_t stream) {
    const float* fm = (const float*)d_in[0];   // fp32 feature_map
    const int*   sw = (const int*)d_in[1];     // int32 switches
    float*       out = (float*)d_out;          // fp32 output

    const int total_threads = BB * CC * HH * (WW / 2);   // 12,845,056
    const int block = 256;
    const int grid  = total_threads / block;             // 50,176 exactly
    unpool_kernel<<<grid, block, 0, stream>>>(fm, sw, out);
}